// Round 10
// baseline (766.374 us; speedup 1.0000x reference)
//
#include <hip/hip_runtime.h>
#include <math.h>

#define N_NODES 100000
#define E_EDGES 1600000
#define E_TOT   (E_EDGES + N_NODES)
#define G_GRAPHS 64
#define IN_DIM 256
#define HID 64
#define HEADS 4
#define D1 256            // HEADS*HID
#define NEG_SLOPE 0.2f
#define SCAN_B 1024
#define CHUNK2 16         // nodes per wave in agg2

typedef float nfloat4 __attribute__((ext_vector_type(4)));
typedef unsigned short nus4 __attribute__((ext_vector_type(4)));
typedef short bf16x8 __attribute__((ext_vector_type(8)));
typedef float f32x4 __attribute__((ext_vector_type(4)));

// bf16 <-> fp32
__device__ __forceinline__ float bf2f(unsigned short u) {
    unsigned int t = ((unsigned int)u) << 16;
    return __builtin_bit_cast(float, t);
}
__device__ __forceinline__ unsigned short f2bf(float f) {
    unsigned int u = __builtin_bit_cast(unsigned int, f);
    u += 0x7FFF + ((u >> 16) & 1);
    return (unsigned short)(u >> 16);
}
// pack 2 fp32 -> 2 bf16 in one dword; add-0x8000 round + v_perm byte-select
// (3 VALU ops; differs from RNE only on exact-tie, 1 ulp)
__device__ __forceinline__ unsigned int pk2(float lo, float hi) {
    unsigned int ul = __builtin_bit_cast(unsigned int, lo) + 0x8000u;
    unsigned int uh = __builtin_bit_cast(unsigned int, hi) + 0x8000u;
    return __builtin_amdgcn_perm(uh, ul, 0x07060302u);   // {uh[3],uh[2],ul[3],ul[2]}
}

// ---------------- MFMA GEMM + fused attention dots, bf16 in/out ----------------
template<int BN, bool ABF16>
__global__ __launch_bounds__(256) void gemm_mfma(const void* __restrict__ Ain,
                                                 const float* __restrict__ B,
                                                 unsigned short* __restrict__ C,
                                                 int Nc,
                                                 const float* __restrict__ att_src,
                                                 const float* __restrict__ att_dst,
                                                 float* __restrict__ a_srcO,
                                                 float* __restrict__ a_dstO,
                                                 int astride)
{
    constexpr int NCG = BN / 16;                  // col-groups
    __shared__ unsigned short alds[4][128][8];    // 8 KB
    __shared__ unsigned short blds[4][BN][8];     // 8/4 KB
    const int tid = threadIdx.x;
    const int lane = tid & 63, wv = tid >> 6;
    const int qd = lane >> 4, c16 = lane & 15;
    const int bm = blockIdx.y * 128, bn = blockIdx.x * BN;

    f32x4 acc[2][NCG];
#pragma unroll
    for (int i = 0; i < 2; ++i)
#pragma unroll
        for (int j = 0; j < NCG; ++j) acc[i][j] = (f32x4){0.f, 0.f, 0.f, 0.f};

    const int ar = tid >> 1, akh = tid & 1;       // A staging: row, k-half
    const int gm = bm + ar;

    for (int k0 = 0; k0 < 256; k0 += 32) {
        // ---- stage A (128 x 32) ----
        if (ABF16) {
            const unsigned short* Ab = (const unsigned short*)Ain + (size_t)gm * 256 + k0 + akh * 16;
            uint4 v0 = make_uint4(0, 0, 0, 0), v1 = v0;
            if (gm < N_NODES) { v0 = *(const uint4*)Ab; v1 = *(const uint4*)(Ab + 8); }
            *(uint4*)&alds[2 * akh][ar][0] = v0;
            *(uint4*)&alds[2 * akh + 1][ar][0] = v1;
        } else {
            const float* Af = (const float*)Ain + (size_t)gm * 256 + k0 + akh * 16;
            float4 f0, f1, f2, f3;
            if (gm < N_NODES) {
                f0 = ((const float4*)Af)[0]; f1 = ((const float4*)Af)[1];
                f2 = ((const float4*)Af)[2]; f3 = ((const float4*)Af)[3];
            } else { f0 = f1 = f2 = f3 = make_float4(0.f, 0.f, 0.f, 0.f); }
            uint4 p0 = make_uint4(pk2(f0.x, f0.y), pk2(f0.z, f0.w), pk2(f1.x, f1.y), pk2(f1.z, f1.w));
            uint4 p1 = make_uint4(pk2(f2.x, f2.y), pk2(f2.z, f2.w), pk2(f3.x, f3.y), pk2(f3.z, f3.w));
            *(uint4*)&alds[2 * akh][ar][0] = p0;
            *(uint4*)&alds[2 * akh + 1][ar][0] = p1;
        }
        // ---- stage B (32 x BN): coalesced k-strided loads, transpose-pack ----
#pragma unroll
        for (int qq = 0; qq < BN / 64; ++qq) {
            const int c = tid & (BN - 1);
            const int q = (tid / BN) * (BN / 64) + qq;
            const float* Bp = B + (size_t)(k0 + q * 8) * Nc + bn + c;
            float b0 = Bp[0 * Nc], b1 = Bp[1 * Nc], b2 = Bp[2 * Nc], b3 = Bp[3 * Nc];
            float b4 = Bp[4 * Nc], b5 = Bp[5 * Nc], b6 = Bp[6 * Nc], b7 = Bp[7 * Nc];
            uint4 pv = make_uint4(pk2(b0, b1), pk2(b2, b3), pk2(b4, b5), pk2(b6, b7));
            *(uint4*)&blds[q][c][0] = pv;
        }
        __syncthreads();

        bf16x8 af0 = *(const bf16x8*)&alds[qd][wv * 32 + c16][0];
        bf16x8 af1 = *(const bf16x8*)&alds[qd][wv * 32 + 16 + c16][0];
#pragma unroll
        for (int cg = 0; cg < NCG; ++cg) {
            bf16x8 bfr = *(const bf16x8*)&blds[qd][cg * 16 + c16][0];
            acc[0][cg] = __builtin_amdgcn_mfma_f32_16x16x32_bf16(af0, bfr, acc[0][cg], 0, 0, 0);
            acc[1][cg] = __builtin_amdgcn_mfma_f32_16x16x32_bf16(af1, bfr, acc[1][cg], 0, 0, 0);
        }
        __syncthreads();
    }

    // ---- epilogue: attention dots (fp32 acc) + bf16 C store ----
    float sv[NCG], dv[NCG];
#pragma unroll
    for (int cg = 0; cg < NCG; ++cg) {
        sv[cg] = att_src[bn + cg * 16 + c16];
        dv[cg] = att_dst[bn + cg * 16 + c16];
    }
#pragma unroll
    for (int rg = 0; rg < 2; ++rg) {
#pragma unroll
        for (int reg = 0; reg < 4; ++reg) {
            const int m = bm + wv * 32 + rg * 16 + qd * 4 + reg;
#pragma unroll
            for (int hh = 0; hh < NCG / 4; ++hh) {
                float ps = 0.f, pd = 0.f;
#pragma unroll
                for (int cg = 4 * hh; cg < 4 * hh + 4; ++cg) {
                    ps += acc[rg][cg][reg] * sv[cg];
                    pd += acc[rg][cg][reg] * dv[cg];
                }
#pragma unroll
                for (int o = 1; o < 16; o <<= 1) { ps += __shfl_xor(ps, o); pd += __shfl_xor(pd, o); }
                if (c16 == 0 && m < N_NODES) {
                    a_srcO[m * astride + (bn >> 6) + hh] = ps;
                    a_dstO[m * astride + (bn >> 6) + hh] = pd;
                }
            }
            if (m < N_NODES) {
#pragma unroll
                for (int cg = 0; cg < NCG; ++cg)
                    C[(size_t)m * Nc + bn + cg * 16 + c16] = f2bf(acc[rg][cg][reg]);
            }
        }
    }
}

// ---------------- CSR build: histogram, scan, scatter ----------------
__global__ void edge_hist(const int* __restrict__ ei, int* __restrict__ deg)
{
    for (int e = blockIdx.x * blockDim.x + threadIdx.x; e < E_TOT; e += gridDim.x * blockDim.x) {
        int d = (e < E_EDGES) ? ei[E_EDGES + e] : (e - E_EDGES);
        atomicAdd(&deg[d], 1);
    }
}

__global__ __launch_bounds__(SCAN_B) void scan_block(const int* __restrict__ deg,
                                                     int* __restrict__ incl,
                                                     int* __restrict__ bsum, int n)
{
    __shared__ int s[SCAN_B];
    int i = blockIdx.x * SCAN_B + threadIdx.x;
    int v = (i < n) ? deg[i] : 0;
    s[threadIdx.x] = v;
    __syncthreads();
    for (int off = 1; off < SCAN_B; off <<= 1) {
        int t = (threadIdx.x >= off) ? s[threadIdx.x - off] : 0;
        __syncthreads();
        s[threadIdx.x] += t;
        __syncthreads();
    }
    if (i < n) incl[i] = s[threadIdx.x];
    if (threadIdx.x == SCAN_B - 1) bsum[blockIdx.x] = s[SCAN_B - 1];
}

__global__ void scan_bsum(const int* __restrict__ bsum, int* __restrict__ bex, int nb)
{
    __shared__ int s[128];
    int i = threadIdx.x;
    int v = (i < nb) ? bsum[i] : 0;
    s[i] = v;
    __syncthreads();
    for (int off = 1; off < 128; off <<= 1) {
        int t = (i >= off) ? s[i - off] : 0;
        __syncthreads();
        s[i] += t;
        __syncthreads();
    }
    if (i < nb) bex[i] = s[i] - v;   // exclusive
}

__global__ void finalize_off(const int* __restrict__ deg, const int* __restrict__ incl,
                             const int* __restrict__ bex, int* __restrict__ off,
                             int* __restrict__ cursor, int n)
{
    int i = blockIdx.x * blockDim.x + threadIdx.x;
    if (i < n) { off[i] = incl[i] - deg[i] + bex[i / SCAN_B]; cursor[i] = 0; }
}

__global__ void edge_scatter(const int* __restrict__ ei, const int* __restrict__ off,
                             int* __restrict__ cursor, int* __restrict__ csr_src)
{
    for (int e = blockIdx.x * blockDim.x + threadIdx.x; e < E_TOT; e += gridDim.x * blockDim.x) {
        int s = (e < E_EDGES) ? ei[e] : (e - E_EDGES);
        int d = (e < E_EDGES) ? ei[E_EDGES + e] : (e - E_EDGES);
        int slot = off[d] + atomicAdd(&cursor[d], 1);
        csr_src[slot] = s;
    }
}

// ---------------- layer-1 aggregation: wave per node (frozen) ----------------
__global__ __launch_bounds__(256) void agg1_kernel(const unsigned short* __restrict__ h1b,
                                                   const int* __restrict__ csr_src,
                                                   const int* __restrict__ off,
                                                   const int* __restrict__ deg,
                                                   const float* __restrict__ a_src,
                                                   const float* __restrict__ a_dst,
                                                   const float* __restrict__ b1,
                                                   unsigned short* __restrict__ hEb)
{
    const int wave = threadIdx.x >> 6, lane = threadIdx.x & 63;
    const int n = blockIdx.x * 4 + wave;
    if (n >= N_NODES) return;
    const int h = lane >> 4;
    const float adn = a_dst[n * 4 + h];
    const int st = off[n], cnt = deg[n];
    float4 acc = make_float4(0.f, 0.f, 0.f, 0.f);
    float dsum = 0.f;

    int s_cur = csr_src[st];                           // deg >= 1 (self-loop)
    int s_nxt = (cnt > 1) ? csr_src[st + 1] : s_cur;
    float a_cur = a_src[s_cur * 4 + h];
    ushort4 v_cur = *(const ushort4*)(h1b + (size_t)s_cur * D1 + lane * 4);

    for (int j = 0; j < cnt; ++j) {
        float a_nxt = a_src[s_nxt * 4 + h];
        ushort4 v_nxt = *(const ushort4*)(h1b + (size_t)s_nxt * D1 + lane * 4);
        int s_n2 = (j + 2 < cnt) ? csr_src[st + j + 2] : s_nxt;

        float al = a_cur + adn;
        al = (al > 0.f) ? al : NEG_SLOPE * al;
        float ex = __expf(al);
        dsum += ex;
        acc.x += ex * bf2f(v_cur.x); acc.y += ex * bf2f(v_cur.y);
        acc.z += ex * bf2f(v_cur.z); acc.w += ex * bf2f(v_cur.w);

        a_cur = a_nxt; v_cur = v_nxt; s_nxt = s_n2;
    }
    const float inv = 1.f / (dsum + 1e-16f);
    float4 bb = *(const float4*)(b1 + lane * 4);
    float ox = acc.x * inv + bb.x;
    float oy = acc.y * inv + bb.y;
    float oz = acc.z * inv + bb.z;
    float ow = acc.w * inv + bb.w;
    ox = (ox > 0.f) ? ox : expm1f(ox);
    oy = (oy > 0.f) ? oy : expm1f(oy);
    oz = (oz > 0.f) ? oz : expm1f(oz);
    ow = (ow > 0.f) ? ow : expm1f(ow);
    nus4 ob = { f2bf(ox), f2bf(oy), f2bf(oz), f2bf(ow) };
    __builtin_nontemporal_store(ob, (nus4*)(hEb + (size_t)n * D1 + lane * 4));
}

// ---------------- layer-2 aggregation + mean-pool: dual-half waves ----------------
// Wave halves process two edges concurrently; each lane covers 2 features via
// ushort2. Halves the serial iteration count (the latency-bound chain) and
// doubles per-lane load width. Halves combined via shfl_xor(32) per node.
__global__ __launch_bounds__(256) void agg2_pool_kernel(const unsigned short* __restrict__ h2b,
                                                        const int* __restrict__ csr_src,
                                                        const int* __restrict__ off,
                                                        const int* __restrict__ deg,
                                                        const float* __restrict__ a_src,
                                                        const float* __restrict__ a_dst,
                                                        const float* __restrict__ b2,
                                                        const int* __restrict__ batch,
                                                        float* __restrict__ pool,
                                                        float* __restrict__ cntg)
{
    const int wave = threadIdx.x >> 6, lane = threadIdx.x & 63;
    const int half = lane >> 5, hl = lane & 31;     // half-id, lane-in-half
    const int f0 = hl * 2;                          // 2 features per lane
    const int wgid = blockIdx.x * 4 + wave;
    const int n0 = wgid * CHUNK2;
    if (n0 >= N_NODES) return;
    const int n1 = (n0 + CHUNK2 < N_NODES) ? n0 + CHUNK2 : N_NODES;
    const float bb0 = b2[f0], bb1 = b2[f0 + 1];

    float pacc0 = 0.f, pacc1 = 0.f, ccur = 0.f;
    int gcur = batch[n0];

    for (int n = n0; n < n1; ++n) {
        const float adn = a_dst[n];
        const int st = off[n], cnt = deg[n];
        const int niter = (cnt + 1) >> 1;
        float acc0 = 0.f, acc1 = 0.f, dsum = 0.f;

        int e = half;                                   // this half's first edge
        bool val_c = e < cnt;
        int s_c = csr_src[st + (val_c ? e : 0)];
        float a_c = a_src[s_c];
        ushort2 v_c = *(const ushort2*)(h2b + (size_t)s_c * HID + f0);

        for (int it = 0; it < niter; ++it) {
            // prefetch next iteration
            int en = e + 2;
            bool val_n = en < cnt;
            int s_n = csr_src[st + (val_n ? en : 0)];
            float a_n = a_src[s_n];
            ushort2 v_n = *(const ushort2*)(h2b + (size_t)s_n * HID + f0);

            float al = a_c + adn;
            al = (al > 0.f) ? al : NEG_SLOPE * al;
            float ex = val_c ? __expf(al) : 0.f;
            dsum += ex;
            acc0 += ex * bf2f(v_c.x);
            acc1 += ex * bf2f(v_c.y);

            e = en; val_c = val_n; s_c = s_n; a_c = a_n; v_c = v_n;
        }
        // combine halves
        dsum += __shfl_xor(dsum, 32);
        acc0 += __shfl_xor(acc0, 32);
        acc1 += __shfl_xor(acc1, 32);

        const float inv = 1.f / (dsum + 1e-16f);
        float v0 = acc0 * inv + bb0;
        float v1 = acc1 * inv + bb1;

        int g = batch[n];
        if (g != gcur) {
            if (half == 0) {
#if defined(__AMDGCN__)
                unsafeAtomicAdd(&pool[gcur * HID + f0], pacc0);
                unsafeAtomicAdd(&pool[gcur * HID + f0 + 1], pacc1);
                if (hl == 0) unsafeAtomicAdd(&cntg[gcur], ccur);
#else
                atomicAdd(&pool[gcur * HID + f0], pacc0);
                atomicAdd(&pool[gcur * HID + f0 + 1], pacc1);
                if (hl == 0) atomicAdd(&cntg[gcur], ccur);
#endif
            }
            pacc0 = 0.f; pacc1 = 0.f; ccur = 0.f; gcur = g;
        }
        pacc0 += v0; pacc1 += v1; ccur += 1.f;
    }
    if (half == 0) {
#if defined(__AMDGCN__)
        unsafeAtomicAdd(&pool[gcur * HID + f0], pacc0);
        unsafeAtomicAdd(&pool[gcur * HID + f0 + 1], pacc1);
        if (hl == 0) unsafeAtomicAdd(&cntg[gcur], ccur);
#else
        atomicAdd(&pool[gcur * HID + f0], pacc0);
        atomicAdd(&pool[gcur * HID + f0 + 1], pacc1);
        if (hl == 0) atomicAdd(&cntg[gcur], ccur);
#endif
    }
}

// ---------------- head: mean, relu MLP, logits ----------------
__global__ void head_kernel(const float* __restrict__ pool, const float* __restrict__ cntg,
                            const float* __restrict__ W3, const float* __restrict__ b3,
                            const float* __restrict__ W4, const float* __restrict__ b4,
                            float* __restrict__ out)
{
    int g = threadIdx.x;
    if (g >= G_GRAPHS) return;
    float invc = 1.f / fmaxf(cntg[g], 1.f);
    float emb[HID];
#pragma unroll
    for (int k = 0; k < HID; ++k) emb[k] = pool[g * HID + k] * invc;
    float z[32];
    for (int j = 0; j < 32; ++j) {
        float s = b3[j];
        for (int k = 0; k < HID; ++k) s += emb[k] * W3[k * 32 + j];
        z[j] = fmaxf(s, 0.f);
    }
    for (int d = 0; d < 2; ++d) {
        float s = b4[d];
        for (int j = 0; j < 32; ++j) s += z[j] * W4[j * 2 + d];
        out[g * 2 + d] = s;
    }
}

extern "C" void kernel_launch(void* const* d_in, const int* in_sizes, int n_in,
                              void* d_out, int out_size, void* d_ws, size_t ws_size,
                              hipStream_t stream)
{
    const float* x     = (const float*)d_in[0];
    const int*   ei    = (const int*)d_in[1];
    const int*   batch = (const int*)d_in[2];
    const float* W1    = (const float*)d_in[3];
    const float* as1w  = (const float*)d_in[4];
    const float* ad1w  = (const float*)d_in[5];
    const float* b1    = (const float*)d_in[6];
    const float* W2    = (const float*)d_in[7];
    const float* as2w  = (const float*)d_in[8];
    const float* ad2w  = (const float*)d_in[9];
    const float* b2    = (const float*)d_in[10];
    const float* W3    = (const float*)d_in[11];
    const float* b3    = (const float*)d_in[12];
    const float* W4    = (const float*)d_in[13];
    const float* b4    = (const float*)d_in[14];
    float* out = (float*)d_out;

    char* ws = (char*)d_ws;
    size_t o = 0;
    auto alloc = [&](size_t bytes) -> void* {
        void* p = ws + o;
        o += (bytes + 255) & ~(size_t)255;
        return p;
    };
    unsigned short* h1b = (unsigned short*)alloc((size_t)N_NODES * D1 * 2);   // bf16 x@W1
    unsigned short* hEb = (unsigned short*)alloc((size_t)N_NODES * D1 * 2);   // bf16 elu(agg1)
    unsigned short* h2b = (unsigned short*)alloc((size_t)N_NODES * HID * 2);  // bf16 hE@W2
    float* a_s1 = (float*)alloc((size_t)N_NODES * 4 * 4);
    float* a_d1 = (float*)alloc((size_t)N_NODES * 4 * 4);
    float* a_s2 = (float*)alloc((size_t)N_NODES * 4);
    float* a_d2 = (float*)alloc((size_t)N_NODES * 4);
    // deg/pool/cntg contiguous -> single memset
    char*  zbase  = (char*)alloc((size_t)N_NODES * 4 + G_GRAPHS * HID * 4 + G_GRAPHS * 4 + 1024);
    int*   deg    = (int*)zbase;
    float* pool   = (float*)(zbase + ((size_t)N_NODES * 4 + 255 & ~(size_t)255));
    float* cntg   = (float*)((char*)pool + ((size_t)G_GRAPHS * HID * 4 + 255 & ~(size_t)255));
    size_t zspan  = (char*)(cntg + G_GRAPHS) - zbase;
    int*   incl   = (int*)alloc((size_t)N_NODES * 4);
    int*   offv   = (int*)alloc((size_t)N_NODES * 4);
    int*   cursor = (int*)alloc((size_t)N_NODES * 4);
    int*   bsum   = (int*)alloc(128 * 4);
    int*   bex    = (int*)alloc(128 * 4);
    int*   csr    = (int*)alloc((size_t)E_TOT * 4);

    (void)hipMemsetAsync(zbase, 0, zspan, stream);

    const int nblk_nodes = (N_NODES + 3) / 4;
    const int nscan = (N_NODES + SCAN_B - 1) / SCAN_B;
    const int nrowblk = (N_NODES + 127) / 128;

    // GEMM1 + att1 (MFMA): h1b = bf16(x) @ bf16(W1), 2 col-tiles of 128
    gemm_mfma<128, false><<<dim3(2, nrowblk), 256, 0, stream>>>(
        x, W1, h1b, D1, as1w, ad1w, a_s1, a_d1, 4);

    // CSR build (shared by both layers)
    edge_hist<<<4096, 256, 0, stream>>>(ei, deg);
    scan_block<<<nscan, SCAN_B, 0, stream>>>(deg, incl, bsum, N_NODES);
    scan_bsum<<<1, 128, 0, stream>>>(bsum, bex, nscan);
    finalize_off<<<(N_NODES + 255) / 256, 256, 0, stream>>>(deg, incl, bex, offv, cursor, N_NODES);
    edge_scatter<<<4096, 256, 0, stream>>>(ei, offv, cursor, csr);

    // layer-1 gather-aggregate (bf16 payload), fused softmax + b1 + ELU, bf16 out
    agg1_kernel<<<nblk_nodes, 256, 0, stream>>>(h1b, csr, offv, deg, a_s1, a_d1, b1, hEb);

    // GEMM2 + att2 (MFMA): h2b = hEb @ bf16(W2), single 64-col tile
    gemm_mfma<64, true><<<dim3(1, nrowblk), 256, 0, stream>>>(
        hEb, W2, h2b, HID, as2w, ad2w, a_s2, a_d2, 1);

    // layer-2 gather-aggregate (dual-half) + register-accumulated mean-pool
    const int nwaves2 = (N_NODES + CHUNK2 - 1) / CHUNK2;
    agg2_pool_kernel<<<(nwaves2 + 3) / 4, 256, 0, stream>>>(h2b, csr, offv, deg, a_s2, a_d2, b2, batch, pool, cntg);

    // head MLP
    head_kernel<<<1, 64, 0, stream>>>(pool, cntg, W3, b3, W4, b4, out);
}

// Round 11
// 719.500 us; speedup vs baseline: 1.0651x; 1.0651x over previous
//
#include <hip/hip_runtime.h>
#include <math.h>

#define N_NODES 100000
#define E_EDGES 1600000
#define E_TOT   (E_EDGES + N_NODES)
#define G_GRAPHS 64
#define IN_DIM 256
#define HID 64
#define HEADS 4
#define D1 256            // HEADS*HID
#define NEG_SLOPE 0.2f
#define SCAN_B 1024
#define CHUNK2 16         // nodes per wave in agg2

typedef float nfloat4 __attribute__((ext_vector_type(4)));
typedef unsigned short nus4 __attribute__((ext_vector_type(4)));
typedef short bf16x8 __attribute__((ext_vector_type(8)));
typedef float f32x4 __attribute__((ext_vector_type(4)));

// bf16 <-> fp32
__device__ __forceinline__ float bf2f(unsigned short u) {
    unsigned int t = ((unsigned int)u) << 16;
    return __builtin_bit_cast(float, t);
}
__device__ __forceinline__ unsigned short f2bf(float f) {
    unsigned int u = __builtin_bit_cast(unsigned int, f);
    u += 0x7FFF + ((u >> 16) & 1);
    return (unsigned short)(u >> 16);
}
// pack 2 fp32 -> 2 bf16 in one dword (add-0x8000 round + v_perm)
__device__ __forceinline__ unsigned int pk2(float lo, float hi) {
    unsigned int ul = __builtin_bit_cast(unsigned int, lo) + 0x8000u;
    unsigned int uh = __builtin_bit_cast(unsigned int, hi) + 0x8000u;
    return __builtin_amdgcn_perm(uh, ul, 0x07060302u);
}

// ---------------- weight pre-pack: W[256][Nc] fp32 -> Wpk[kg][n][8] bf16 ----------------
// Wpk[(kg*Nc + n)*8 + j] = bf16(W[kg*8 + j][n])  -> one dwordx4 = a full B-fragment slice.
__global__ __launch_bounds__(256) void convW(const float* __restrict__ W,
                                             unsigned short* __restrict__ Wpk, int Nc)
{
    int t = blockIdx.x * 256 + threadIdx.x;
    if (t >= 32 * Nc) return;
    int kg = t / Nc, n = t - kg * Nc;
    const float* p = W + (size_t)(kg * 8) * Nc + n;
    uint4 v;
    v.x = pk2(p[0],      p[Nc]);
    v.y = pk2(p[2 * Nc], p[3 * Nc]);
    v.z = pk2(p[4 * Nc], p[5 * Nc]);
    v.w = pk2(p[6 * Nc], p[7 * Nc]);
    *(uint4*)(Wpk + (size_t)t * 8) = v;
}

// ---------------- MFMA GEMM + fused attention dots ----------------
// C[M,Nc](bf16) = A[M,256] @ W; W pre-packed (B-frags loaded straight from L2).
// A double-buffered in LDS, ONE barrier per k-step. 128xBN tile, 4 waves.
template<int BN, bool ABF16>
__global__ __launch_bounds__(256) void gemm_mfma(const void* __restrict__ Ain,
                                                 const unsigned short* __restrict__ Wpk,
                                                 unsigned short* __restrict__ C,
                                                 int Nc,
                                                 const float* __restrict__ att_src,
                                                 const float* __restrict__ att_dst,
                                                 float* __restrict__ a_srcO,
                                                 float* __restrict__ a_dstO,
                                                 int astride)
{
    constexpr int NCG = BN / 16;                  // col-groups
    __shared__ unsigned short alds[2][4][128][8]; // 16 KB, double-buffered
    const int tid = threadIdx.x;
    const int lane = tid & 63, wv = tid >> 6;
    const int qd = lane >> 4, c16 = lane & 15;
    const int bm = blockIdx.y * 128, bn = blockIdx.x * BN;

    f32x4 acc[2][NCG];
#pragma unroll
    for (int i = 0; i < 2; ++i)
#pragma unroll
        for (int j = 0; j < NCG; ++j) acc[i][j] = (f32x4){0.f, 0.f, 0.f, 0.f};

    const int ar = tid >> 1, akh = tid & 1;       // A staging: row, k-half
    const int gm = bm + ar;
    const bool mv = gm < N_NODES;

    // prefetch regs for A
    uint4 v0, v1;                                  // ABF16 path
    float4 f0, f1, f2, f3;                         // fp32 path
    if (ABF16) {
        const unsigned short* Ab = (const unsigned short*)Ain + (size_t)gm * 256 + akh * 16;
        v0 = mv ? *(const uint4*)Ab : make_uint4(0, 0, 0, 0);
        v1 = mv ? *(const uint4*)(Ab + 8) : make_uint4(0, 0, 0, 0);
    } else {
        const float* Af = (const float*)Ain + (size_t)gm * 256 + akh * 16;
        if (mv) { f0 = ((const float4*)Af)[0]; f1 = ((const float4*)Af)[1];
                  f2 = ((const float4*)Af)[2]; f3 = ((const float4*)Af)[3]; }
        else { f0 = f1 = f2 = f3 = make_float4(0.f, 0.f, 0.f, 0.f); }
    }

    for (int k0 = 0; k0 < 256; k0 += 32) {
        const int p = (k0 >> 5) & 1;
        if (ABF16) {
            *(uint4*)&alds[p][2 * akh][ar][0] = v0;
            *(uint4*)&alds[p][2 * akh + 1][ar][0] = v1;
        } else {
            uint4 p0 = make_uint4(pk2(f0.x, f0.y), pk2(f0.z, f0.w), pk2(f1.x, f1.y), pk2(f1.z, f1.w));
            uint4 p1 = make_uint4(pk2(f2.x, f2.y), pk2(f2.z, f2.w), pk2(f3.x, f3.y), pk2(f3.z, f3.w));
            *(uint4*)&alds[p][2 * akh][ar][0] = p0;
            *(uint4*)&alds[p][2 * akh + 1][ar][0] = p1;
        }
        __syncthreads();

        if (k0 + 32 < 256) {                      // prefetch next A k-chunk
            if (ABF16) {
                const unsigned short* Ab = (const unsigned short*)Ain + (size_t)gm * 256 + (k0 + 32) + akh * 16;
                v0 = mv ? *(const uint4*)Ab : make_uint4(0, 0, 0, 0);
                v1 = mv ? *(const uint4*)(Ab + 8) : make_uint4(0, 0, 0, 0);
            } else {
                const float* Af = (const float*)Ain + (size_t)gm * 256 + (k0 + 32) + akh * 16;
                if (mv) { f0 = ((const float4*)Af)[0]; f1 = ((const float4*)Af)[1];
                          f2 = ((const float4*)Af)[2]; f3 = ((const float4*)Af)[3]; }
            }
        }

        // B-fragments straight from pre-packed global (L2-hot)
        const unsigned short* Wq = Wpk + ((size_t)((k0 >> 3) + qd) * Nc + bn) * 8;
        bf16x8 af0 = *(const bf16x8*)&alds[p][qd][wv * 32 + c16][0];
        bf16x8 af1 = *(const bf16x8*)&alds[p][qd][wv * 32 + 16 + c16][0];
#pragma unroll
        for (int cg = 0; cg < NCG; ++cg) {
            bf16x8 bfr = *(const bf16x8*)(Wq + (size_t)(cg * 16 + c16) * 8);
            acc[0][cg] = __builtin_amdgcn_mfma_f32_16x16x32_bf16(af0, bfr, acc[0][cg], 0, 0, 0);
            acc[1][cg] = __builtin_amdgcn_mfma_f32_16x16x32_bf16(af1, bfr, acc[1][cg], 0, 0, 0);
        }
    }

    // ---- epilogue: attention dots (fp32 acc) + bf16 C store ----
    float sv[NCG], dv[NCG];
#pragma unroll
    for (int cg = 0; cg < NCG; ++cg) {
        sv[cg] = att_src[bn + cg * 16 + c16];
        dv[cg] = att_dst[bn + cg * 16 + c16];
    }
#pragma unroll
    for (int rg = 0; rg < 2; ++rg) {
#pragma unroll
        for (int reg = 0; reg < 4; ++reg) {
            const int m = bm + wv * 32 + rg * 16 + qd * 4 + reg;
#pragma unroll
            for (int hh = 0; hh < NCG / 4; ++hh) {
                float ps = 0.f, pd = 0.f;
#pragma unroll
                for (int cg = 4 * hh; cg < 4 * hh + 4; ++cg) {
                    ps += acc[rg][cg][reg] * sv[cg];
                    pd += acc[rg][cg][reg] * dv[cg];
                }
#pragma unroll
                for (int o = 1; o < 16; o <<= 1) { ps += __shfl_xor(ps, o); pd += __shfl_xor(pd, o); }
                if (c16 == 0 && m < N_NODES) {
                    a_srcO[m * astride + (bn >> 6) + hh] = ps;
                    a_dstO[m * astride + (bn >> 6) + hh] = pd;
                }
            }
            if (m < N_NODES) {
#pragma unroll
                for (int cg = 0; cg < NCG; ++cg)
                    C[(size_t)m * Nc + bn + cg * 16 + c16] = f2bf(acc[rg][cg][reg]);
            }
        }
    }
}

// ---------------- CSR build: histogram(+rank), scan, atomic-free scatter ----------------
__global__ void edge_hist(const int* __restrict__ ei, int* __restrict__ deg,
                          int* __restrict__ rank)
{
    for (int e = blockIdx.x * blockDim.x + threadIdx.x; e < E_TOT; e += gridDim.x * blockDim.x) {
        int d = (e < E_EDGES) ? ei[E_EDGES + e] : (e - E_EDGES);
        rank[e] = atomicAdd(&deg[d], 1);
    }
}

__global__ __launch_bounds__(SCAN_B) void scan_block(const int* __restrict__ deg,
                                                     int* __restrict__ incl,
                                                     int* __restrict__ bsum, int n)
{
    __shared__ int s[SCAN_B];
    int i = blockIdx.x * SCAN_B + threadIdx.x;
    int v = (i < n) ? deg[i] : 0;
    s[threadIdx.x] = v;
    __syncthreads();
    for (int off = 1; off < SCAN_B; off <<= 1) {
        int t = (threadIdx.x >= off) ? s[threadIdx.x - off] : 0;
        __syncthreads();
        s[threadIdx.x] += t;
        __syncthreads();
    }
    if (i < n) incl[i] = s[threadIdx.x];
    if (threadIdx.x == SCAN_B - 1) bsum[blockIdx.x] = s[SCAN_B - 1];
}

__global__ void scan_bsum(const int* __restrict__ bsum, int* __restrict__ bex, int nb)
{
    __shared__ int s[128];
    int i = threadIdx.x;
    int v = (i < nb) ? bsum[i] : 0;
    s[i] = v;
    __syncthreads();
    for (int off = 1; off < 128; off <<= 1) {
        int t = (i >= off) ? s[i - off] : 0;
        __syncthreads();
        s[i] += t;
        __syncthreads();
    }
    if (i < nb) bex[i] = s[i] - v;   // exclusive
}

__global__ void finalize_off(const int* __restrict__ deg, const int* __restrict__ incl,
                             const int* __restrict__ bex, int* __restrict__ off, int n)
{
    int i = blockIdx.x * blockDim.x + threadIdx.x;
    if (i < n) off[i] = incl[i] - deg[i] + bex[i / SCAN_B];
}

__global__ void edge_scatter(const int* __restrict__ ei, const int* __restrict__ off,
                             const int* __restrict__ rank, int* __restrict__ csr_src)
{
    for (int e = blockIdx.x * blockDim.x + threadIdx.x; e < E_TOT; e += gridDim.x * blockDim.x) {
        int s = (e < E_EDGES) ? ei[e] : (e - E_EDGES);
        int d = (e < E_EDGES) ? ei[E_EDGES + e] : (e - E_EDGES);
        csr_src[off[d] + rank[e]] = s;
    }
}

// ---------------- layer-1 aggregation: wave per node (frozen) ----------------
__global__ __launch_bounds__(256) void agg1_kernel(const unsigned short* __restrict__ h1b,
                                                   const int* __restrict__ csr_src,
                                                   const int* __restrict__ off,
                                                   const int* __restrict__ deg,
                                                   const float* __restrict__ a_src,
                                                   const float* __restrict__ a_dst,
                                                   const float* __restrict__ b1,
                                                   unsigned short* __restrict__ hEb)
{
    const int wave = threadIdx.x >> 6, lane = threadIdx.x & 63;
    const int n = blockIdx.x * 4 + wave;
    if (n >= N_NODES) return;
    const int h = lane >> 4;
    const float adn = a_dst[n * 4 + h];
    const int st = off[n], cnt = deg[n];
    float4 acc = make_float4(0.f, 0.f, 0.f, 0.f);
    float dsum = 0.f;

    int s_cur = csr_src[st];                           // deg >= 1 (self-loop)
    int s_nxt = (cnt > 1) ? csr_src[st + 1] : s_cur;
    float a_cur = a_src[s_cur * 4 + h];
    ushort4 v_cur = *(const ushort4*)(h1b + (size_t)s_cur * D1 + lane * 4);

    for (int j = 0; j < cnt; ++j) {
        float a_nxt = a_src[s_nxt * 4 + h];
        ushort4 v_nxt = *(const ushort4*)(h1b + (size_t)s_nxt * D1 + lane * 4);
        int s_n2 = (j + 2 < cnt) ? csr_src[st + j + 2] : s_nxt;

        float al = a_cur + adn;
        al = (al > 0.f) ? al : NEG_SLOPE * al;
        float ex = __expf(al);
        dsum += ex;
        acc.x += ex * bf2f(v_cur.x); acc.y += ex * bf2f(v_cur.y);
        acc.z += ex * bf2f(v_cur.z); acc.w += ex * bf2f(v_cur.w);

        a_cur = a_nxt; v_cur = v_nxt; s_nxt = s_n2;
    }
    const float inv = 1.f / (dsum + 1e-16f);
    float4 bb = *(const float4*)(b1 + lane * 4);
    float ox = acc.x * inv + bb.x;
    float oy = acc.y * inv + bb.y;
    float oz = acc.z * inv + bb.z;
    float ow = acc.w * inv + bb.w;
    ox = (ox > 0.f) ? ox : expm1f(ox);
    oy = (oy > 0.f) ? oy : expm1f(oy);
    oz = (oz > 0.f) ? oz : expm1f(oz);
    ow = (ow > 0.f) ? ow : expm1f(ow);
    nus4 ob = { f2bf(ox), f2bf(oy), f2bf(oz), f2bf(ow) };
    __builtin_nontemporal_store(ob, (nus4*)(hEb + (size_t)n * D1 + lane * 4));
}

// ---------------- layer-2 aggregation + mean-pool: dual-half waves ----------------
__global__ __launch_bounds__(256) void agg2_pool_kernel(const unsigned short* __restrict__ h2b,
                                                        const int* __restrict__ csr_src,
                                                        const int* __restrict__ off,
                                                        const int* __restrict__ deg,
                                                        const float* __restrict__ a_src,
                                                        const float* __restrict__ a_dst,
                                                        const float* __restrict__ b2,
                                                        const int* __restrict__ batch,
                                                        float* __restrict__ pool,
                                                        float* __restrict__ cntg)
{
    const int wave = threadIdx.x >> 6, lane = threadIdx.x & 63;
    const int half = lane >> 5, hl = lane & 31;
    const int f0 = hl * 2;
    const int wgid = blockIdx.x * 4 + wave;
    const int n0 = wgid * CHUNK2;
    if (n0 >= N_NODES) return;
    const int n1 = (n0 + CHUNK2 < N_NODES) ? n0 + CHUNK2 : N_NODES;
    const float bb0 = b2[f0], bb1 = b2[f0 + 1];

    float pacc0 = 0.f, pacc1 = 0.f, ccur = 0.f;
    int gcur = batch[n0];

    for (int n = n0; n < n1; ++n) {
        const float adn = a_dst[n];
        const int st = off[n], cnt = deg[n];
        const int niter = (cnt + 1) >> 1;
        float acc0 = 0.f, acc1 = 0.f, dsum = 0.f;

        int e = half;
        bool val_c = e < cnt;
        int s_c = csr_src[st + (val_c ? e : 0)];
        float a_c = a_src[s_c];
        ushort2 v_c = *(const ushort2*)(h2b + (size_t)s_c * HID + f0);

        for (int it = 0; it < niter; ++it) {
            int en = e + 2;
            bool val_n = en < cnt;
            int s_n = csr_src[st + (val_n ? en : 0)];
            float a_n = a_src[s_n];
            ushort2 v_n = *(const ushort2*)(h2b + (size_t)s_n * HID + f0);

            float al = a_c + adn;
            al = (al > 0.f) ? al : NEG_SLOPE * al;
            float ex = val_c ? __expf(al) : 0.f;
            dsum += ex;
            acc0 += ex * bf2f(v_c.x);
            acc1 += ex * bf2f(v_c.y);

            e = en; val_c = val_n; s_c = s_n; a_c = a_n; v_c = v_n;
        }
        dsum += __shfl_xor(dsum, 32);
        acc0 += __shfl_xor(acc0, 32);
        acc1 += __shfl_xor(acc1, 32);

        const float inv = 1.f / (dsum + 1e-16f);
        float v0 = acc0 * inv + bb0;
        float v1 = acc1 * inv + bb1;

        int g = batch[n];
        if (g != gcur) {
            if (half == 0) {
#if defined(__AMDGCN__)
                unsafeAtomicAdd(&pool[gcur * HID + f0], pacc0);
                unsafeAtomicAdd(&pool[gcur * HID + f0 + 1], pacc1);
                if (hl == 0) unsafeAtomicAdd(&cntg[gcur], ccur);
#else
                atomicAdd(&pool[gcur * HID + f0], pacc0);
                atomicAdd(&pool[gcur * HID + f0 + 1], pacc1);
                if (hl == 0) atomicAdd(&cntg[gcur], ccur);
#endif
            }
            pacc0 = 0.f; pacc1 = 0.f; ccur = 0.f; gcur = g;
        }
        pacc0 += v0; pacc1 += v1; ccur += 1.f;
    }
    if (half == 0) {
#if defined(__AMDGCN__)
        unsafeAtomicAdd(&pool[gcur * HID + f0], pacc0);
        unsafeAtomicAdd(&pool[gcur * HID + f0 + 1], pacc1);
        if (hl == 0) unsafeAtomicAdd(&cntg[gcur], ccur);
#else
        atomicAdd(&pool[gcur * HID + f0], pacc0);
        atomicAdd(&pool[gcur * HID + f0 + 1], pacc1);
        if (hl == 0) atomicAdd(&cntg[gcur], ccur);
#endif
    }
}

// ---------------- head: mean, relu MLP, logits ----------------
__global__ void head_kernel(const float* __restrict__ pool, const float* __restrict__ cntg,
                            const float* __restrict__ W3, const float* __restrict__ b3,
                            const float* __restrict__ W4, const float* __restrict__ b4,
                            float* __restrict__ out)
{
    int g = threadIdx.x;
    if (g >= G_GRAPHS) return;
    float invc = 1.f / fmaxf(cntg[g], 1.f);
    float emb[HID];
#pragma unroll
    for (int k = 0; k < HID; ++k) emb[k] = pool[g * HID + k] * invc;
    float z[32];
    for (int j = 0; j < 32; ++j) {
        float s = b3[j];
        for (int k = 0; k < HID; ++k) s += emb[k] * W3[k * 32 + j];
        z[j] = fmaxf(s, 0.f);
    }
    for (int d = 0; d < 2; ++d) {
        float s = b4[d];
        for (int j = 0; j < 32; ++j) s += z[j] * W4[j * 2 + d];
        out[g * 2 + d] = s;
    }
}

extern "C" void kernel_launch(void* const* d_in, const int* in_sizes, int n_in,
                              void* d_out, int out_size, void* d_ws, size_t ws_size,
                              hipStream_t stream)
{
    const float* x     = (const float*)d_in[0];
    const int*   ei    = (const int*)d_in[1];
    const int*   batch = (const int*)d_in[2];
    const float* W1    = (const float*)d_in[3];
    const float* as1w  = (const float*)d_in[4];
    const float* ad1w  = (const float*)d_in[5];
    const float* b1    = (const float*)d_in[6];
    const float* W2    = (const float*)d_in[7];
    const float* as2w  = (const float*)d_in[8];
    const float* ad2w  = (const float*)d_in[9];
    const float* b2    = (const float*)d_in[10];
    const float* W3    = (const float*)d_in[11];
    const float* b3    = (const float*)d_in[12];
    const float* W4    = (const float*)d_in[13];
    const float* b4    = (const float*)d_in[14];
    float* out = (float*)d_out;

    char* ws = (char*)d_ws;
    size_t o = 0;
    auto alloc = [&](size_t bytes) -> void* {
        void* p = ws + o;
        o += (bytes + 255) & ~(size_t)255;
        return p;
    };
    unsigned short* h1b = (unsigned short*)alloc((size_t)N_NODES * D1 * 2);
    unsigned short* hEb = (unsigned short*)alloc((size_t)N_NODES * D1 * 2);
    unsigned short* h2b = (unsigned short*)alloc((size_t)N_NODES * HID * 2);
    float* a_s1 = (float*)alloc((size_t)N_NODES * 4 * 4);
    float* a_d1 = (float*)alloc((size_t)N_NODES * 4 * 4);
    float* a_s2 = (float*)alloc((size_t)N_NODES * 4);
    float* a_d2 = (float*)alloc((size_t)N_NODES * 4);
    // deg/pool/cntg contiguous -> single memset
    char*  zbase  = (char*)alloc((size_t)N_NODES * 4 + G_GRAPHS * HID * 4 + G_GRAPHS * 4 + 1024);
    int*   deg    = (int*)zbase;
    float* pool   = (float*)(zbase + (((size_t)N_NODES * 4 + 255) & ~(size_t)255));
    float* cntg   = (float*)((char*)pool + (((size_t)G_GRAPHS * HID * 4 + 255) & ~(size_t)255));
    size_t zspan  = (char*)(cntg + G_GRAPHS) - zbase;
    int*   incl   = (int*)alloc((size_t)N_NODES * 4);
    int*   offv   = (int*)alloc((size_t)N_NODES * 4);
    int*   rank   = (int*)alloc((size_t)E_TOT * 4);
    int*   bsum   = (int*)alloc(128 * 4);
    int*   bex    = (int*)alloc(128 * 4);
    int*   csr    = (int*)alloc((size_t)E_TOT * 4);
    unsigned short* Wpk1 = (unsigned short*)alloc((size_t)32 * D1 * 8 * 2);   // 128 KB
    unsigned short* Wpk2 = (unsigned short*)alloc((size_t)32 * HID * 8 * 2);  // 32 KB

    (void)hipMemsetAsync(zbase, 0, zspan, stream);

    const int nblk_nodes = (N_NODES + 3) / 4;
    const int nscan = (N_NODES + SCAN_B - 1) / SCAN_B;
    const int nrowblk = (N_NODES + 127) / 128;

    // pre-pack weights into MFMA B-fragment layout
    convW<<<(32 * D1 + 255) / 256, 256, 0, stream>>>(W1, Wpk1, D1);
    convW<<<(32 * HID + 255) / 256, 256, 0, stream>>>(W2, Wpk2, HID);

    // GEMM1 + att1 (MFMA): h1b = bf16(x) @ Wpk1, 2 col-tiles of 128
    gemm_mfma<128, false><<<dim3(2, nrowblk), 256, 0, stream>>>(
        x, Wpk1, h1b, D1, as1w, ad1w, a_s1, a_d1, 4);

    // CSR build: hist records per-edge rank -> scatter is atomic-free
    edge_hist<<<4096, 256, 0, stream>>>(ei, deg, rank);
    scan_block<<<nscan, SCAN_B, 0, stream>>>(deg, incl, bsum, N_NODES);
    scan_bsum<<<1, 128, 0, stream>>>(bsum, bex, nscan);
    finalize_off<<<(N_NODES + 255) / 256, 256, 0, stream>>>(deg, incl, bex, offv, N_NODES);
    edge_scatter<<<4096, 256, 0, stream>>>(ei, offv, rank, csr);

    // layer-1 gather-aggregate (bf16 payload), fused softmax + b1 + ELU, bf16 out
    agg1_kernel<<<nblk_nodes, 256, 0, stream>>>(h1b, csr, offv, deg, a_s1, a_d1, b1, hEb);

    // GEMM2 + att2 (MFMA): h2b = hEb @ Wpk2, single 64-col tile
    gemm_mfma<64, true><<<dim3(1, nrowblk), 256, 0, stream>>>(
        hEb, Wpk2, h2b, HID, as2w, ad2w, a_s2, a_d2, 1);

    // layer-2 gather-aggregate (dual-half) + register-accumulated mean-pool
    const int nwaves2 = (N_NODES + CHUNK2 - 1) / CHUNK2;
    agg2_pool_kernel<<<(nwaves2 + 3) / 4, 256, 0, stream>>>(h2b, csr, offv, deg, a_s2, a_d2, b2, batch, pool, cntg);

    // head MLP
    head_kernel<<<1, 64, 0, stream>>>(pool, cntg, W3, b3, W4, b4, out);
}